// Round 18
// baseline (119.080 us; speedup 1.0000x reference)
//
#include <hip/hip_runtime.h>
#include <hip/hip_bf16.h>

typedef __attribute__((ext_vector_type(8))) short bf16x8;
typedef __attribute__((ext_vector_type(4))) float f32x4;
typedef unsigned int u32;

#define L_SEQ 2048
#define NHEAD 8
#define DHEAD 64
#define DMODEL 512
#define QK_STRIDE 262144          // per-nh shorts, frag-major Q/K (2048*128)
#define V_STRIDE  131072          // per-nh shorts, frag-major V (2048*64)

__device__ __forceinline__ short f2bf(float f) {
    union { float f; unsigned u; } x; x.f = f;
    unsigned r = x.u + 0x7FFFu + ((x.u >> 16) & 1u);
    return (short)(r >> 16);
}

__device__ __forceinline__ void split1(float x, short& hi, short& lo) {
    unsigned uh = __float_as_uint(x) & 0xFFFF0000u;
    hi = (short)(uh >> 16);
    lo = f2bf(x - __uint_as_float(uh));
}

__device__ __forceinline__ void split8(const float* p, bf16x8& hi, bf16x8& lo) {
    #pragma unroll
    for (int i = 0; i < 8; ++i) {
        float x = p[i];
        unsigned uh = __float_as_uint(x) & 0xFFFF0000u;
        hi[i] = (short)(uh >> 16);
        lo[i] = f2bf(x - __uint_as_float(uh));
    }
}

__device__ __forceinline__ u32 cvtpk_bf16(float a, float b) {
    u32 r;
    asm("v_cvt_pk_bf16_f32 %0, %1, %2" : "=v"(r) : "v"(a), "v"(b));
    return r;
}

// async global->LDS, 16B per lane, wave-uniform LDS base (HW adds lane*16)
__device__ __forceinline__ void gload_lds16(const void* g, void* l) {
    __builtin_amdgcn_global_load_lds(
        (const __attribute__((address_space(1))) unsigned int*)g,
        (__attribute__((address_space(3))) unsigned int*)l, 16, 0, 0);
}

// ---------------------------------------------------------------------------
// Kernel 0: one-time split of y / W into frag-major bf16 hi/lo arrays.
// ---------------------------------------------------------------------------
__global__ __launch_bounds__(256) void split_kernel(
    const float* __restrict__ y,
    const float* __restrict__ Wq, const float* __restrict__ Wk, const float* __restrict__ Wv,
    short* __restrict__ yh, short* __restrict__ yl,
    short* __restrict__ wh, short* __restrict__ wl)
{
    const int wv = threadIdx.x >> 6, ln = threadIdx.x & 63;
    const int u = blockIdx.x * 4 + wv;          // 0..5631
    float tmp[8];
    if (u < 4096) {
        const int B = u >> 4, kb = u & 15;
        const int row = B*16 + (ln & 15);
        const int k   = kb*32 + (ln >> 4)*8;
        const float* src = y + (size_t)row * DMODEL + k;
        *(float4*)tmp       = *(const float4*)src;
        *(float4*)(tmp + 4) = *(const float4*)(src + 4);
        bf16x8 hi, lo;
        split8(tmp, hi, lo);
        const size_t dst = (size_t)u*512 + ln*8;
        *(bf16x8*)(yh + dst) = hi;
        *(bf16x8*)(yl + dst) = lo;
    } else {
        const int u2 = u - 4096;                // 0..1535
        const int mat = u2 >> 9;
        const int r   = u2 & 511;
        const int C = r >> 4, kb = r & 15;
        const float* W = (mat == 0) ? Wq : (mat == 1) ? Wk : Wv;
        const int col = C*16 + (ln & 15);
        const int k   = kb*32 + (ln >> 4)*8;
        const float* src = W + (size_t)col * DMODEL + k;
        *(float4*)tmp       = *(const float4*)src;
        *(float4*)(tmp + 4) = *(const float4*)(src + 4);
        bf16x8 hi, lo;
        split8(tmp, hi, lo);
        const size_t dst = (size_t)u2*512 + ln*8;
        *(bf16x8*)(wh + dst) = hi;
        *(bf16x8*)(wl + dst) = lo;
    }
}

// ---------------------------------------------------------------------------
// Kernel 1: C = y @ W^T, pure bf16 3-term MFMA from pre-split frag-major
// arrays. Epilogues write FRAG-MAJOR layouts for attn. Grid (32, 8, 3).
// ---------------------------------------------------------------------------
__global__ __launch_bounds__(256) void prep_kernel(
    const short* __restrict__ yh, const short* __restrict__ yl,
    const short* __restrict__ wh, const short* __restrict__ wl,
    const float* __restrict__ positions,
    const float* __restrict__ coeff, const float* __restrict__ pw, const float* __restrict__ pb,
    short* __restrict__ Qh, short* __restrict__ Ql,
    short* __restrict__ Kh, short* __restrict__ Kl,
    short* __restrict__ Vh, short* __restrict__ Vl)
{
    __shared__ float vtile[128][65];
    const int mode = blockIdx.z;
    const int m_base = blockIdx.x * 128;
    const int h = blockIdx.y;
    const int n_base = h * 64;
    const int tid = threadIdx.x;
    const int lane = tid & 63;
    const int wv = tid >> 6;
    const int lr = lane & 15;
    const int lg = lane >> 4;

    const short* whm = wh + (size_t)mode * 262144;
    const short* wlm = wl + (size_t)mode * 262144;
    const int Ba0 = blockIdx.x*8 + wv*2;

    f32x4 acc[2][4];
    #pragma unroll
    for (int t = 0; t < 2; ++t)
        #pragma unroll
        for (int c = 0; c < 4; ++c) acc[t][c] = (f32x4){0.f, 0.f, 0.f, 0.f};

    #pragma unroll 4
    for (int kb = 0; kb < 16; ++kb) {
        bf16x8 ah[2], al[2], bh[4], bl[4];
        #pragma unroll
        for (int t = 0; t < 2; ++t) {
            const size_t off = ((size_t)((Ba0 + t)*16 + kb)*64 + lane)*8;
            ah[t] = *(const bf16x8*)(yh + off);
            al[t] = *(const bf16x8*)(yl + off);
        }
        #pragma unroll
        for (int c = 0; c < 4; ++c) {
            const size_t off = ((size_t)((h*4 + c)*16 + kb)*64 + lane)*8;
            bh[c] = *(const bf16x8*)(whm + off);
            bl[c] = *(const bf16x8*)(wlm + off);
        }
        #pragma unroll
        for (int t = 0; t < 2; ++t)
            #pragma unroll
            for (int c = 0; c < 4; ++c) {
                acc[t][c] = __builtin_amdgcn_mfma_f32_16x16x32_bf16(ah[t], bh[c], acc[t][c], 0, 0, 0);
                acc[t][c] = __builtin_amdgcn_mfma_f32_16x16x32_bf16(ah[t], bl[c], acc[t][c], 0, 0, 0);
                acc[t][c] = __builtin_amdgcn_mfma_f32_16x16x32_bf16(al[t], bh[c], acc[t][c], 0, 0, 0);
            }
    }

    const int n_idx = m_base >> 11;
    const int nh = n_idx * NHEAD + h;

    if (mode == 2) {
        #pragma unroll
        for (int t = 0; t < 2; ++t)
            #pragma unroll
            for (int c = 0; c < 4; ++c)
                #pragma unroll
                for (int r = 0; r < 4; ++r)
                    vtile[wv*32 + t*16 + lg*4 + r][c*16 + lr] = acc[t][c][r];
        __syncthreads();
        const size_t vbase = (size_t)nh * V_STRIDE;
        #pragma unroll
        for (int i = 0; i < 32; ++i) {
            const int key_l = (tid & 7) + 8*(i & 15);          // 0..127
            const int d     = (tid >> 3) + 32*(i >> 4);        // 0..63
            const int key   = (m_base & (L_SEQ - 1)) + key_l;
            short th, tl;
            split1(vtile[key_l][d], th, tl);
            const size_t idx = vbase +
                ((size_t)((key >> 5)*4 + (d >> 4))*64 + (d & 15) + 16*((key >> 3) & 3))*8 + (key & 7);
            Vh[idx] = th; Vl[idx] = tl;
        }
    } else {
        short* OUTh = (mode == 0) ? Qh : Kh;
        short* OUTl = (mode == 0) ? Ql : Kl;
        const size_t qbase_nh = (size_t)nh * QK_STRIDE;
        #pragma unroll
        for (int t = 0; t < 2; ++t) {
            #pragma unroll
            for (int c = 0; c < 4; ++c) {
                const int d = c*16 + lr;
                const float pwv = pw[n_base + d];
                const float pbv = pb[n_base + d];
                const float cf  = (mode == 0) ? coeff[n_base + d] : 1.0f;
                const int lane_t = 16*((2*c + (lr >> 3)) & 3);
                const int j = lr & 7;
                #pragma unroll
                for (int r = 0; r < 4; ++r) {
                    const int gm = m_base + wv*32 + t*16 + lg*4 + r;
                    const int l = gm & (L_SEQ - 1);
                    const int B = l >> 4;
                    const float posv = positions[gm];
                    const float x = acc[t][c][r];
                    const float sp = fmaxf(x, 0.f) + __logf(1.f + __expf(-fabsf(x)));
                    const float p = pwv * posv + pbv;
                    const float cs = __cosf(p), sn = __sinf(p);
                    short h1, l1, h2, l2;
                    split1(sp * cf * cs, h1, l1);
                    split1(sp * cf * sn, h2, l2);
                    const int ln = (l & 15) + lane_t;
                    const size_t idx_c = qbase_nh + ((size_t)(B*4 + (c >> 1))*64 + ln)*8 + j;
                    const size_t idx_s = qbase_nh + ((size_t)(B*4 + 2 + (c >> 1))*64 + ln)*8 + j;
                    OUTh[idx_c] = h1; OUTl[idx_c] = l1;
                    OUTh[idx_s] = h2; OUTl[idx_s] = l2;
                }
            }
        }
    }
}

// ---------------------------------------------------------------------------
// Kernel 2: split-K causal attention. R18: EXACT R15 structure (best measured:
// 56.7us — 8 waves x 16 q-rows, K hi+lo double-buffered 2x32KB LDS, one
// barrier/kstep, V direct global, XCD decode, CHUNK=4) + T5 s_setprio around
// both MFMA clusters (R15 has 4 desynced waves/SIMD -> T5's prerequisite).
// ---------------------------------------------------------------------------
template<int CHUNK>
__global__ __launch_bounds__(512) void attn_kernel(
    const short* __restrict__ Qh, const short* __restrict__ Ql,
    const short* __restrict__ Kh, const short* __restrict__ Kl,
    const short* __restrict__ Vh, const short* __restrict__ Vl,
    float* __restrict__ O_part, float* __restrict__ rs_part)
{
    __shared__ char s_lds[65536];   // 2 x (K-hi 16KB | K-lo 16KB)
    const int id = blockIdx.x;
    const int nh   = (id & 7)*2 + ((id >> 3) & 1);
    const int slot = id >> 4;

    int rem = slot, qt = 0;
    for (qt = 0; qt < 16; ++qt) {
        const int nch = (2*qt + 2 + CHUNK - 1) / CHUNK;
        if (rem < nch) break;
        rem -= nch;
    }
    const int nst = 2*qt + 2;
    const int kt0 = rem * CHUNK;
    const int kt1 = (kt0 + CHUNK < nst) ? (kt0 + CHUNK) : nst;

    const int q_base = qt * 128;
    const int tid = threadIdx.x;
    const int lane = tid & 63;
    const int wv = tid >> 6;          // 0..7
    const int lr = lane & 15;
    const int lg = lane >> 4;

    const short* Qh_b = Qh + (size_t)nh * QK_STRIDE;
    const short* Ql_b = Ql + (size_t)nh * QK_STRIDE;
    const short* Kh_b = Kh + (size_t)nh * QK_STRIDE;
    const short* Kl_b = Kl + (size_t)nh * QK_STRIDE;
    const short* Vh_b = Vh + (size_t)nh * V_STRIDE;
    const short* Vl_b = Vl + (size_t)nh * V_STRIDE;

    // Q fragments: one 16-row block per wave
    bf16x8 qh[4], ql[4];
    {
        const int Bq = qt*8 + wv;
        #pragma unroll
        for (int kh = 0; kh < 4; ++kh) {
            const size_t off = ((size_t)(Bq*4 + kh)*64 + lane)*8;
            qh[kh] = *(const bf16x8*)(Qh_b + off);
            ql[kh] = *(const bf16x8*)(Ql_b + off);
        }
    }

    f32x4 o_acc[4];
    float rs = 0.f;
    #pragma unroll
    for (int c = 0; c < 4; ++c) o_acc[c] = (f32x4){0.f, 0.f, 0.f, 0.f};

    const int addr0 = (lr + ((lg & 1) * 2) * 16) << 2;
    const int addr1 = addr0 + 64;
    const bool selhi = (lg >= 2);
    const int lb = lane << 4;

    // prologue: stage K hi+lo (kt0) into buffer 0 (32 chunks / 8 waves = 4 each)
    {
        const char* kh_src = (const char*)(Kh_b + (size_t)kt0*8192);
        const char* kl_src = (const char*)(Kl_b + (size_t)kt0*8192);
        #pragma unroll
        for (int i = 0; i < 4; ++i) {
            const int ch = wv*4 + i;                  // 0..31
            const char* src = (ch < 16) ? kh_src + ch*1024 : kl_src + (ch-16)*1024;
            gload_lds16(src + lb, s_lds + ch*1024);
        }
    }
    __syncthreads();

    int cur = 0;
    for (int kt = kt0; kt < kt1; ++kt) {
        // issue next-kstep K stage into the other buffer (hidden under compute)
        if (kt + 1 < kt1) {
            const char* kh_src = (const char*)(Kh_b + (size_t)(kt+1)*8192);
            const char* kl_src = (const char*)(Kl_b + (size_t)(kt+1)*8192);
            char* dst = s_lds + (cur ? 0 : 32768);
            #pragma unroll
            for (int i = 0; i < 4; ++i) {
                const int ch = wv*4 + i;
                const char* src = (ch < 16) ? kh_src + ch*1024 : kl_src + (ch-16)*1024;
                gload_lds16(src + lb, dst + ch*1024);
            }
        }

        // V frag loads for this kstep (global, L2-resident; hidden under QK)
        bf16x8 vfh[2][4], vfl[2][4];
        #pragma unroll
        for (int kc = 0; kc < 2; ++kc)
            #pragma unroll
            for (int cd = 0; cd < 4; ++cd) {
                const size_t voff = ((size_t)((kt*2 + kc)*4 + cd)*64 + lane)*8;
                vfh[kc][cd] = *(const bf16x8*)(Vh_b + voff);
                vfl[kc][cd] = *(const bf16x8*)(Vl_b + voff);
            }

        // ---- QK^T (swapped) from LDS buffer cur ----
        const char* kbuf = s_lds + (cur ? 32768 : 0);
        f32x4 st[4];
        #pragma unroll
        for (int c = 0; c < 4; ++c) st[c] = (f32x4){0.f, 0.f, 0.f, 0.f};

        #pragma unroll
        for (int c = 0; c < 4; ++c) {
            __builtin_amdgcn_s_setprio(1);
            #pragma unroll
            for (int kh = 0; kh < 4; ++kh) {
                const int boff = (c*4 + kh)*1024 + lb;
                const bf16x8 kfh = *(const bf16x8*)(kbuf + boff);
                const bf16x8 kfl = *(const bf16x8*)(kbuf + 16384 + boff);
                st[c] = __builtin_amdgcn_mfma_f32_16x16x32_bf16(kfh, qh[kh], st[c], 0, 0, 0);
                st[c] = __builtin_amdgcn_mfma_f32_16x16x32_bf16(kfh, ql[kh], st[c], 0, 0, 0);
                st[c] = __builtin_amdgcn_mfma_f32_16x16x32_bf16(kfl, qh[kh], st[c], 0, 0, 0);
            }
            __builtin_amdgcn_s_setprio(0);
        }

        // ---- mask + rowsum ----
        const int k0 = kt * 64;
        const bool domask = (kt >= 2*qt);
        {
            const int gq = q_base + wv*16 + lr;
            float part = 0.f;
            #pragma unroll
            for (int c = 0; c < 4; ++c)
                #pragma unroll
                for (int r = 0; r < 4; ++r) {
                    const int gk = k0 + c*16 + lg*4 + r;
                    float v = st[c][r];
                    if (domask && gk > gq) v = 0.f;
                    st[c][r] = v;
                    part += v;
                }
            part += __shfl_xor(part, 16);
            part += __shfl_xor(part, 32);
            rs += part;
        }

        // ---- pack S^T to bf16 hi/lo words ----
        u32 pwh[4][2], pwl[4][2];
        #pragma unroll
        for (int c = 0; c < 4; ++c) {
            const u32 b0 = __float_as_uint(st[c][0]);
            const u32 b1 = __float_as_uint(st[c][1]);
            const u32 b2 = __float_as_uint(st[c][2]);
            const u32 b3 = __float_as_uint(st[c][3]);
            pwh[c][0] = (b1 & 0xFFFF0000u) | (b0 >> 16);
            pwh[c][1] = (b3 & 0xFFFF0000u) | (b2 >> 16);
            const float l0 = st[c][0] - __uint_as_float(b0 & 0xFFFF0000u);
            const float l1 = st[c][1] - __uint_as_float(b1 & 0xFFFF0000u);
            const float l2 = st[c][2] - __uint_as_float(b2 & 0xFFFF0000u);
            const float l3 = st[c][3] - __uint_as_float(b3 & 0xFFFF0000u);
            pwl[c][0] = cvtpk_bf16(l0, l1);
            pwl[c][1] = cvtpk_bf16(l2, l3);
        }

        // ---- PV: gather PA frags via bpermute, V from registers ----
        #pragma unroll
        for (int kc = 0; kc < 2; ++kc) {
            union { u32 u[4]; bf16x8 v; } pah, pal;
            u32 a, b;
            a = (u32)__builtin_amdgcn_ds_bpermute(addr0, (int)pwh[2*kc][0]);
            b = (u32)__builtin_amdgcn_ds_bpermute(addr0, (int)pwh[2*kc+1][0]);
            pah.u[0] = selhi ? b : a;
            a = (u32)__builtin_amdgcn_ds_bpermute(addr0, (int)pwh[2*kc][1]);
            b = (u32)__builtin_amdgcn_ds_bpermute(addr0, (int)pwh[2*kc+1][1]);
            pah.u[1] = selhi ? b : a;
            a = (u32)__builtin_amdgcn_ds_bpermute(addr1, (int)pwh[2*kc][0]);
            b = (u32)__builtin_amdgcn_ds_bpermute(addr1, (int)pwh[2*kc+1][0]);
            pah.u[2] = selhi ? b : a;
            a = (u32)__builtin_amdgcn_ds_bpermute(addr1, (int)pwh[2*kc][1]);
            b = (u32)__builtin_amdgcn_ds_bpermute(addr1, (int)pwh[2*kc+1][1]);
            pah.u[3] = selhi ? b : a;

            a = (u32)__builtin_amdgcn_ds_bpermute(addr0, (int)pwl[2*kc][0]);
            b = (u32)__builtin_amdgcn_ds_bpermute(addr0, (int)pwl[2*kc+1][0]);
            pal.u[0] = selhi ? b : a;
            a = (u32)__builtin_amdgcn_ds_bpermute(addr0, (int)pwl[2*kc][1]);
            b = (u32)__builtin_amdgcn_ds_bpermute(addr0, (int)pwl[2*kc+1][1]);
            pal.u[1] = selhi ? b : a;
            a = (u32)__builtin_amdgcn_ds_bpermute(addr1, (int)pwl[2*kc][0]);
            b = (u32)__builtin_amdgcn_ds_bpermute(addr1, (int)pwl[2*kc+1][0]);
            pal.u[2] = selhi ? b : a;
            a = (u32)__builtin_amdgcn_ds_bpermute(addr1, (int)pwl[2*kc][1]);
            b = (u32)__builtin_amdgcn_ds_bpermute(addr1, (int)pwl[2*kc+1][1]);
            pal.u[3] = selhi ? b : a;

            __builtin_amdgcn_s_setprio(1);
            #pragma unroll
            for (int cd = 0; cd < 4; ++cd) {
                o_acc[cd] = __builtin_amdgcn_mfma_f32_16x16x32_bf16(pah.v, vfh[kc][cd], o_acc[cd], 0, 0, 0);
                o_acc[cd] = __builtin_amdgcn_mfma_f32_16x16x32_bf16(pah.v, vfl[kc][cd], o_acc[cd], 0, 0, 0);
                o_acc[cd] = __builtin_amdgcn_mfma_f32_16x16x32_bf16(pal.v, vfh[kc][cd], o_acc[cd], 0, 0, 0);
            }
            __builtin_amdgcn_s_setprio(0);
        }
        __syncthreads();   // drains vmcnt: next K staged & visible; buffer safe
        cur ^= 1;
    }

    const size_t slab = (size_t)slot * 16 + nh;
    if (lg == 0)
        rs_part[slab*128 + wv*16 + lr] = rs;

    #pragma unroll
    for (int cd = 0; cd < 4; ++cd)
        #pragma unroll
        for (int r = 0; r < 4; ++r) {
            const int row = wv*16 + lg*4 + r;
            O_part[slab*8192 + row*64 + cd*16 + lr] = o_acc[cd][r];
        }
}

// Reduce chunk partials per (nh,qt), divide by rowsum, write output.
template<int CHUNK>
__global__ __launch_bounds__(256) void reduce_div_kernel(
    const float* __restrict__ O_part, const float* __restrict__ rs_part,
    float* __restrict__ out)
{
    const int idx = blockIdx.x * 256 + threadIdx.x;
    const int d4 = idx & 15;
    const int l  = (idx >> 4) & (L_SEQ - 1);
    const int nh = idx >> 15;
    const int qt = l >> 7;
    const int row = l & 127;
    int cs = 0;
    for (int q = 0; q < qt; ++q) cs += (2*q + 2 + CHUNK - 1) / CHUNK;
    const int nch = (2*qt + 2 + CHUNK - 1) / CHUNK;

    float4 o = {0.f, 0.f, 0.f, 0.f};
    float rssum = 0.f;
    for (int ci = 0; ci < nch; ++ci) {
        const size_t slab = (size_t)(cs + ci) * 16 + nh;
        const float4 p = *(const float4*)(O_part + slab*8192 + row*64 + d4*4);
        o.x += p.x; o.y += p.y; o.z += p.z; o.w += p.w;
        rssum += rs_part[slab*128 + row];
    }
    const float inv = 1.0f / rssum;
    float4 r;
    r.x = o.x * inv; r.y = o.y * inv; r.z = o.z * inv; r.w = o.w * inv;
    const int n = nh >> 3, h = nh & 7;
    *(float4*)(out + ((size_t)(n*L_SEQ + l))*DMODEL + h*DHEAD + d4*4) = r;
}

extern "C" void kernel_launch(void* const* d_in, const int* in_sizes, int n_in,
                              void* d_out, int out_size, void* d_ws, size_t ws_size,
                              hipStream_t stream) {
    const float* y         = (const float*)d_in[0];
    const float* positions = (const float*)d_in[1];
    const float* Wq        = (const float*)d_in[2];
    const float* Wk        = (const float*)d_in[3];
    const float* Wv        = (const float*)d_in[4];
    const float* coeff     = (const float*)d_in[5];
    const float* pw        = (const float*)d_in[6];
    const float* pb        = (const float*)d_in[7];
    float* out = (float*)d_out;

    const size_t SQK = (size_t)16 * QK_STRIDE;   // shorts (8 MB)
    const size_t SV  = (size_t)16 * V_STRIDE;    // shorts (4 MB)
    const size_t SY  = (size_t)4096 * 512;       // 2M shorts (4 MB)
    const size_t SW  = (size_t)3 * 512 * 512;    // 768K shorts (1.5 MB)
    short* Qh = (short*)d_ws;
    short* Ql = Qh + SQK;
    short* Kh = Ql + SQK;
    short* Kl = Kh + SQK;
    short* Vh = Kl + SQK;
    short* Vl = Vh + SV;
    short* yh = Vl + SV;
    short* yl = yh + SY;
    short* wh = yl + SY;
    short* wl = wh + SW;
    float* O_part = (float*)(wl + SW);
    const size_t base_bytes = (SQK*4 + SV*2 + SY*2 + SW*2) * sizeof(short);
    const size_t per_slot   = (size_t)16 * (8192 + 128) * sizeof(float);

    split_kernel<<<dim3(1408), dim3(256), 0, stream>>>(y, Wq, Wk, Wv, yh, yl, wh, wl);
    prep_kernel<<<dim3(32, 8, 3), dim3(256), 0, stream>>>(
        yh, yl, wh, wl, positions, coeff, pw, pb, Qh, Ql, Kh, Kl, Vh, Vl);

    if (ws_size >= base_bytes + 72 * per_slot) {
        float* rs_part = O_part + (size_t)72 * 16 * 8192;
        attn_kernel<4><<<dim3(72 * 16), dim3(512), 0, stream>>>(
            Qh, Ql, Kh, Kl, Vh, Vl, O_part, rs_part);
        reduce_div_kernel<4><<<dim3(2048), dim3(256), 0, stream>>>(O_part, rs_part, out);
    } else {
        float* rs_part = O_part + (size_t)40 * 16 * 8192;
        attn_kernel<8><<<dim3(40 * 16), dim3(512), 0, stream>>>(
            Qh, Ql, Kh, Kl, Vh, Vl, O_part, rs_part);
        reduce_div_kernel<8><<<dim3(2048), dim3(256), 0, stream>>>(O_part, rs_part, out);
    }
}

// Round 19
// 95.527 us; speedup vs baseline: 1.2466x; 1.2466x over previous
//
#include <hip/hip_runtime.h>
#include <hip/hip_bf16.h>

typedef __attribute__((ext_vector_type(8))) short bf16x8;
typedef __attribute__((ext_vector_type(4))) float f32x4;
typedef unsigned int u32;

#define L_SEQ 2048
#define NHEAD 8
#define DHEAD 64
#define DMODEL 512
#define QK_STRIDE 262144          // per-nh shorts, frag-major Q/K (2048*128)
#define V_STRIDE  131072          // per-nh shorts, frag-major V (2048*64)

__device__ __forceinline__ short f2bf(float f) {
    union { float f; unsigned u; } x; x.f = f;
    unsigned r = x.u + 0x7FFFu + ((x.u >> 16) & 1u);
    return (short)(r >> 16);
}

__device__ __forceinline__ void split1(float x, short& hi, short& lo) {
    unsigned uh = __float_as_uint(x) & 0xFFFF0000u;
    hi = (short)(uh >> 16);
    lo = f2bf(x - __uint_as_float(uh));
}

__device__ __forceinline__ void split8(const float* p, bf16x8& hi, bf16x8& lo) {
    #pragma unroll
    for (int i = 0; i < 8; ++i) {
        float x = p[i];
        unsigned uh = __float_as_uint(x) & 0xFFFF0000u;
        hi[i] = (short)(uh >> 16);
        lo[i] = f2bf(x - __uint_as_float(uh));
    }
}

__device__ __forceinline__ u32 cvtpk_bf16(float a, float b) {
    u32 r;
    asm("v_cvt_pk_bf16_f32 %0, %1, %2" : "=v"(r) : "v"(a), "v"(b));
    return r;
}

// async global->LDS, 16B per lane, wave-uniform LDS base (HW adds lane*16)
__device__ __forceinline__ void gload_lds16(const void* g, void* l) {
    __builtin_amdgcn_global_load_lds(
        (const __attribute__((address_space(1))) unsigned int*)g,
        (__attribute__((address_space(3))) unsigned int*)l, 16, 0, 0);
}

// ---------------------------------------------------------------------------
// Kernel 0: one-time split of y / W into frag-major bf16 hi/lo arrays.
// ---------------------------------------------------------------------------
__global__ __launch_bounds__(256) void split_kernel(
    const float* __restrict__ y,
    const float* __restrict__ Wq, const float* __restrict__ Wk, const float* __restrict__ Wv,
    short* __restrict__ yh, short* __restrict__ yl,
    short* __restrict__ wh, short* __restrict__ wl)
{
    const int wv = threadIdx.x >> 6, ln = threadIdx.x & 63;
    const int u = blockIdx.x * 4 + wv;          // 0..5631
    float tmp[8];
    if (u < 4096) {
        const int B = u >> 4, kb = u & 15;
        const int row = B*16 + (ln & 15);
        const int k   = kb*32 + (ln >> 4)*8;
        const float* src = y + (size_t)row * DMODEL + k;
        *(float4*)tmp       = *(const float4*)src;
        *(float4*)(tmp + 4) = *(const float4*)(src + 4);
        bf16x8 hi, lo;
        split8(tmp, hi, lo);
        const size_t dst = (size_t)u*512 + ln*8;
        *(bf16x8*)(yh + dst) = hi;
        *(bf16x8*)(yl + dst) = lo;
    } else {
        const int u2 = u - 4096;                // 0..1535
        const int mat = u2 >> 9;
        const int r   = u2 & 511;
        const int C = r >> 4, kb = r & 15;
        const float* W = (mat == 0) ? Wq : (mat == 1) ? Wk : Wv;
        const int col = C*16 + (ln & 15);
        const int k   = kb*32 + (ln >> 4)*8;
        const float* src = W + (size_t)col * DMODEL + k;
        *(float4*)tmp       = *(const float4*)src;
        *(float4*)(tmp + 4) = *(const float4*)(src + 4);
        bf16x8 hi, lo;
        split8(tmp, hi, lo);
        const size_t dst = (size_t)u2*512 + ln*8;
        *(bf16x8*)(wh + dst) = hi;
        *(bf16x8*)(wl + dst) = lo;
    }
}

// ---------------------------------------------------------------------------
// Kernel 1: C = y @ W^T, pure bf16 3-term MFMA from pre-split frag-major
// arrays. Epilogues write FRAG-MAJOR layouts for attn. Grid (32, 8, 3).
// ---------------------------------------------------------------------------
__global__ __launch_bounds__(256) void prep_kernel(
    const short* __restrict__ yh, const short* __restrict__ yl,
    const short* __restrict__ wh, const short* __restrict__ wl,
    const float* __restrict__ positions,
    const float* __restrict__ coeff, const float* __restrict__ pw, const float* __restrict__ pb,
    short* __restrict__ Qh, short* __restrict__ Ql,
    short* __restrict__ Kh, short* __restrict__ Kl,
    short* __restrict__ Vh, short* __restrict__ Vl)
{
    __shared__ float vtile[128][65];
    const int mode = blockIdx.z;
    const int m_base = blockIdx.x * 128;
    const int h = blockIdx.y;
    const int n_base = h * 64;
    const int tid = threadIdx.x;
    const int lane = tid & 63;
    const int wv = tid >> 6;
    const int lr = lane & 15;
    const int lg = lane >> 4;

    const short* whm = wh + (size_t)mode * 262144;
    const short* wlm = wl + (size_t)mode * 262144;
    const int Ba0 = blockIdx.x*8 + wv*2;

    f32x4 acc[2][4];
    #pragma unroll
    for (int t = 0; t < 2; ++t)
        #pragma unroll
        for (int c = 0; c < 4; ++c) acc[t][c] = (f32x4){0.f, 0.f, 0.f, 0.f};

    #pragma unroll 4
    for (int kb = 0; kb < 16; ++kb) {
        bf16x8 ah[2], al[2], bh[4], bl[4];
        #pragma unroll
        for (int t = 0; t < 2; ++t) {
            const size_t off = ((size_t)((Ba0 + t)*16 + kb)*64 + lane)*8;
            ah[t] = *(const bf16x8*)(yh + off);
            al[t] = *(const bf16x8*)(yl + off);
        }
        #pragma unroll
        for (int c = 0; c < 4; ++c) {
            const size_t off = ((size_t)((h*4 + c)*16 + kb)*64 + lane)*8;
            bh[c] = *(const bf16x8*)(whm + off);
            bl[c] = *(const bf16x8*)(wlm + off);
        }
        #pragma unroll
        for (int t = 0; t < 2; ++t)
            #pragma unroll
            for (int c = 0; c < 4; ++c) {
                acc[t][c] = __builtin_amdgcn_mfma_f32_16x16x32_bf16(ah[t], bh[c], acc[t][c], 0, 0, 0);
                acc[t][c] = __builtin_amdgcn_mfma_f32_16x16x32_bf16(ah[t], bl[c], acc[t][c], 0, 0, 0);
                acc[t][c] = __builtin_amdgcn_mfma_f32_16x16x32_bf16(al[t], bh[c], acc[t][c], 0, 0, 0);
            }
    }

    const int n_idx = m_base >> 11;
    const int nh = n_idx * NHEAD + h;

    if (mode == 2) {
        #pragma unroll
        for (int t = 0; t < 2; ++t)
            #pragma unroll
            for (int c = 0; c < 4; ++c)
                #pragma unroll
                for (int r = 0; r < 4; ++r)
                    vtile[wv*32 + t*16 + lg*4 + r][c*16 + lr] = acc[t][c][r];
        __syncthreads();
        const size_t vbase = (size_t)nh * V_STRIDE;
        #pragma unroll
        for (int i = 0; i < 32; ++i) {
            const int key_l = (tid & 7) + 8*(i & 15);          // 0..127
            const int d     = (tid >> 3) + 32*(i >> 4);        // 0..63
            const int key   = (m_base & (L_SEQ - 1)) + key_l;
            short th, tl;
            split1(vtile[key_l][d], th, tl);
            const size_t idx = vbase +
                ((size_t)((key >> 5)*4 + (d >> 4))*64 + (d & 15) + 16*((key >> 3) & 3))*8 + (key & 7);
            Vh[idx] = th; Vl[idx] = tl;
        }
    } else {
        short* OUTh = (mode == 0) ? Qh : Kh;
        short* OUTl = (mode == 0) ? Ql : Kl;
        const size_t qbase_nh = (size_t)nh * QK_STRIDE;
        #pragma unroll
        for (int t = 0; t < 2; ++t) {
            #pragma unroll
            for (int c = 0; c < 4; ++c) {
                const int d = c*16 + lr;
                const float pwv = pw[n_base + d];
                const float pbv = pb[n_base + d];
                const float cf  = (mode == 0) ? coeff[n_base + d] : 1.0f;
                const int lane_t = 16*((2*c + (lr >> 3)) & 3);
                const int j = lr & 7;
                #pragma unroll
                for (int r = 0; r < 4; ++r) {
                    const int gm = m_base + wv*32 + t*16 + lg*4 + r;
                    const int l = gm & (L_SEQ - 1);
                    const int B = l >> 4;
                    const float posv = positions[gm];
                    const float x = acc[t][c][r];
                    const float sp = fmaxf(x, 0.f) + __logf(1.f + __expf(-fabsf(x)));
                    const float p = pwv * posv + pbv;
                    const float cs = __cosf(p), sn = __sinf(p);
                    short h1, l1, h2, l2;
                    split1(sp * cf * cs, h1, l1);
                    split1(sp * cf * sn, h2, l2);
                    const int ln = (l & 15) + lane_t;
                    const size_t idx_c = qbase_nh + ((size_t)(B*4 + (c >> 1))*64 + ln)*8 + j;
                    const size_t idx_s = qbase_nh + ((size_t)(B*4 + 2 + (c >> 1))*64 + ln)*8 + j;
                    OUTh[idx_c] = h1; OUTl[idx_c] = l1;
                    OUTh[idx_s] = h2; OUTl[idx_s] = l2;
                }
            }
        }
    }
}

// ---------------------------------------------------------------------------
// Kernel 2: split-K causal attention. R19 = EXACT R15 (best measured: attn
// 56.7us, total 95.6us): 8 waves x 16 q-rows, K hi+lo double-buffered 2x32KB
// LDS, one barrier/kstep, V direct global, XCD decode, CHUNK=4, no setprio
// (R18 proved setprio fences regress this barrier-synced structure).
// ---------------------------------------------------------------------------
template<int CHUNK>
__global__ __launch_bounds__(512) void attn_kernel(
    const short* __restrict__ Qh, const short* __restrict__ Ql,
    const short* __restrict__ Kh, const short* __restrict__ Kl,
    const short* __restrict__ Vh, const short* __restrict__ Vl,
    float* __restrict__ O_part, float* __restrict__ rs_part)
{
    __shared__ char s_lds[65536];   // 2 x (K-hi 16KB | K-lo 16KB)
    const int id = blockIdx.x;
    const int nh   = (id & 7)*2 + ((id >> 3) & 1);
    const int slot = id >> 4;

    int rem = slot, qt = 0;
    for (qt = 0; qt < 16; ++qt) {
        const int nch = (2*qt + 2 + CHUNK - 1) / CHUNK;
        if (rem < nch) break;
        rem -= nch;
    }
    const int nst = 2*qt + 2;
    const int kt0 = rem * CHUNK;
    const int kt1 = (kt0 + CHUNK < nst) ? (kt0 + CHUNK) : nst;

    const int q_base = qt * 128;
    const int tid = threadIdx.x;
    const int lane = tid & 63;
    const int wv = tid >> 6;          // 0..7
    const int lr = lane & 15;
    const int lg = lane >> 4;

    const short* Qh_b = Qh + (size_t)nh * QK_STRIDE;
    const short* Ql_b = Ql + (size_t)nh * QK_STRIDE;
    const short* Kh_b = Kh + (size_t)nh * QK_STRIDE;
    const short* Kl_b = Kl + (size_t)nh * QK_STRIDE;
    const short* Vh_b = Vh + (size_t)nh * V_STRIDE;
    const short* Vl_b = Vl + (size_t)nh * V_STRIDE;

    // Q fragments: one 16-row block per wave
    bf16x8 qh[4], ql[4];
    {
        const int Bq = qt*8 + wv;
        #pragma unroll
        for (int kh = 0; kh < 4; ++kh) {
            const size_t off = ((size_t)(Bq*4 + kh)*64 + lane)*8;
            qh[kh] = *(const bf16x8*)(Qh_b + off);
            ql[kh] = *(const bf16x8*)(Ql_b + off);
        }
    }

    f32x4 o_acc[4];
    float rs = 0.f;
    #pragma unroll
    for (int c = 0; c < 4; ++c) o_acc[c] = (f32x4){0.f, 0.f, 0.f, 0.f};

    const int addr0 = (lr + ((lg & 1) * 2) * 16) << 2;
    const int addr1 = addr0 + 64;
    const bool selhi = (lg >= 2);
    const int lb = lane << 4;

    // prologue: stage K hi+lo (kt0) into buffer 0 (32 chunks / 8 waves = 4 each)
    {
        const char* kh_src = (const char*)(Kh_b + (size_t)kt0*8192);
        const char* kl_src = (const char*)(Kl_b + (size_t)kt0*8192);
        #pragma unroll
        for (int i = 0; i < 4; ++i) {
            const int ch = wv*4 + i;                  // 0..31
            const char* src = (ch < 16) ? kh_src + ch*1024 : kl_src + (ch-16)*1024;
            gload_lds16(src + lb, s_lds + ch*1024);
        }
    }
    __syncthreads();

    int cur = 0;
    for (int kt = kt0; kt < kt1; ++kt) {
        // issue next-kstep K stage into the other buffer (hidden under compute)
        if (kt + 1 < kt1) {
            const char* kh_src = (const char*)(Kh_b + (size_t)(kt+1)*8192);
            const char* kl_src = (const char*)(Kl_b + (size_t)(kt+1)*8192);
            char* dst = s_lds + (cur ? 0 : 32768);
            #pragma unroll
            for (int i = 0; i < 4; ++i) {
                const int ch = wv*4 + i;
                const char* src = (ch < 16) ? kh_src + ch*1024 : kl_src + (ch-16)*1024;
                gload_lds16(src + lb, dst + ch*1024);
            }
        }

        // V frag loads for this kstep (global, L2-resident; hidden under QK)
        bf16x8 vfh[2][4], vfl[2][4];
        #pragma unroll
        for (int kc = 0; kc < 2; ++kc)
            #pragma unroll
            for (int cd = 0; cd < 4; ++cd) {
                const size_t voff = ((size_t)((kt*2 + kc)*4 + cd)*64 + lane)*8;
                vfh[kc][cd] = *(const bf16x8*)(Vh_b + voff);
                vfl[kc][cd] = *(const bf16x8*)(Vl_b + voff);
            }

        // ---- QK^T (swapped) from LDS buffer cur ----
        const char* kbuf = s_lds + (cur ? 32768 : 0);
        f32x4 st[4];
        #pragma unroll
        for (int c = 0; c < 4; ++c) st[c] = (f32x4){0.f, 0.f, 0.f, 0.f};

        #pragma unroll
        for (int c = 0; c < 4; ++c) {
            #pragma unroll
            for (int kh = 0; kh < 4; ++kh) {
                const int boff = (c*4 + kh)*1024 + lb;
                const bf16x8 kfh = *(const bf16x8*)(s_lds + (cur ? 32768 : 0) + boff);
                const bf16x8 kfl = *(const bf16x8*)(kbuf + 16384 + boff);
                st[c] = __builtin_amdgcn_mfma_f32_16x16x32_bf16(kfh, qh[kh], st[c], 0, 0, 0);
                st[c] = __builtin_amdgcn_mfma_f32_16x16x32_bf16(kfh, ql[kh], st[c], 0, 0, 0);
                st[c] = __builtin_amdgcn_mfma_f32_16x16x32_bf16(kfl, qh[kh], st[c], 0, 0, 0);
            }
        }

        // ---- mask + rowsum ----
        const int k0 = kt * 64;
        const bool domask = (kt >= 2*qt);
        {
            const int gq = q_base + wv*16 + lr;
            float part = 0.f;
            #pragma unroll
            for (int c = 0; c < 4; ++c)
                #pragma unroll
                for (int r = 0; r < 4; ++r) {
                    const int gk = k0 + c*16 + lg*4 + r;
                    float v = st[c][r];
                    if (domask && gk > gq) v = 0.f;
                    st[c][r] = v;
                    part += v;
                }
            part += __shfl_xor(part, 16);
            part += __shfl_xor(part, 32);
            rs += part;
        }

        // ---- pack S^T to bf16 hi/lo words ----
        u32 pwh[4][2], pwl[4][2];
        #pragma unroll
        for (int c = 0; c < 4; ++c) {
            const u32 b0 = __float_as_uint(st[c][0]);
            const u32 b1 = __float_as_uint(st[c][1]);
            const u32 b2 = __float_as_uint(st[c][2]);
            const u32 b3 = __float_as_uint(st[c][3]);
            pwh[c][0] = (b1 & 0xFFFF0000u) | (b0 >> 16);
            pwh[c][1] = (b3 & 0xFFFF0000u) | (b2 >> 16);
            const float l0 = st[c][0] - __uint_as_float(b0 & 0xFFFF0000u);
            const float l1 = st[c][1] - __uint_as_float(b1 & 0xFFFF0000u);
            const float l2 = st[c][2] - __uint_as_float(b2 & 0xFFFF0000u);
            const float l3 = st[c][3] - __uint_as_float(b3 & 0xFFFF0000u);
            pwl[c][0] = cvtpk_bf16(l0, l1);
            pwl[c][1] = cvtpk_bf16(l2, l3);
        }

        // ---- PV: gather PA frags via bpermute, V from registers ----
        #pragma unroll
        for (int kc = 0; kc < 2; ++kc) {
            union { u32 u[4]; bf16x8 v; } pah, pal;
            u32 a, b;
            a = (u32)__builtin_amdgcn_ds_bpermute(addr0, (int)pwh[2*kc][0]);
            b = (u32)__builtin_amdgcn_ds_bpermute(addr0, (int)pwh[2*kc+1][0]);
            pah.u[0] = selhi ? b : a;
            a = (u32)__builtin_amdgcn_ds_bpermute(addr0, (int)pwh[2*kc][1]);
            b = (u32)__builtin_amdgcn_ds_bpermute(addr0, (int)pwh[2*kc+1][1]);
            pah.u[1] = selhi ? b : a;
            a = (u32)__builtin_amdgcn_ds_bpermute(addr1, (int)pwh[2*kc][0]);
            b = (u32)__builtin_amdgcn_ds_bpermute(addr1, (int)pwh[2*kc+1][0]);
            pah.u[2] = selhi ? b : a;
            a = (u32)__builtin_amdgcn_ds_bpermute(addr1, (int)pwh[2*kc][1]);
            b = (u32)__builtin_amdgcn_ds_bpermute(addr1, (int)pwh[2*kc+1][1]);
            pah.u[3] = selhi ? b : a;

            a = (u32)__builtin_amdgcn_ds_bpermute(addr0, (int)pwl[2*kc][0]);
            b = (u32)__builtin_amdgcn_ds_bpermute(addr0, (int)pwl[2*kc+1][0]);
            pal.u[0] = selhi ? b : a;
            a = (u32)__builtin_amdgcn_ds_bpermute(addr0, (int)pwl[2*kc][1]);
            b = (u32)__builtin_amdgcn_ds_bpermute(addr0, (int)pwl[2*kc+1][1]);
            pal.u[1] = selhi ? b : a;
            a = (u32)__builtin_amdgcn_ds_bpermute(addr1, (int)pwl[2*kc][0]);
            b = (u32)__builtin_amdgcn_ds_bpermute(addr1, (int)pwl[2*kc+1][0]);
            pal.u[2] = selhi ? b : a;
            a = (u32)__builtin_amdgcn_ds_bpermute(addr1, (int)pwl[2*kc][1]);
            b = (u32)__builtin_amdgcn_ds_bpermute(addr1, (int)pwl[2*kc+1][1]);
            pal.u[3] = selhi ? b : a;

            #pragma unroll
            for (int cd = 0; cd < 4; ++cd) {
                o_acc[cd] = __builtin_amdgcn_mfma_f32_16x16x32_bf16(pah.v, vfh[kc][cd], o_acc[cd], 0, 0, 0);
                o_acc[cd] = __builtin_amdgcn_mfma_f32_16x16x32_bf16(pah.v, vfl[kc][cd], o_acc[cd], 0, 0, 0);
                o_acc[cd] = __builtin_amdgcn_mfma_f32_16x16x32_bf16(pal.v, vfh[kc][cd], o_acc[cd], 0, 0, 0);
            }
        }
        __syncthreads();   // drains vmcnt: next K staged & visible; buffer safe
        cur ^= 1;
    }

    const size_t slab = (size_t)slot * 16 + nh;
    if (lg == 0)
        rs_part[slab*128 + wv*16 + lr] = rs;

    #pragma unroll
    for (int cd = 0; cd < 4; ++cd)
        #pragma unroll
        for (int r = 0; r < 4; ++r) {
            const int row = wv*16 + lg*4 + r;
            O_part[slab*8192 + row*64 + cd*16 + lr] = o_acc[cd][r];
        }
}

// Reduce chunk partials per (nh,qt), divide by rowsum, write output.
template<int CHUNK>
__global__ __launch_bounds__(256) void reduce_div_kernel(
    const float* __restrict__ O_part, const float* __restrict__ rs_part,
    float* __restrict__ out)
{
    const int idx = blockIdx.x * 256 + threadIdx.x;
    const int d4 = idx & 15;
    const int l  = (idx >> 4) & (L_SEQ - 1);
    const int nh = idx >> 15;
    const int qt = l >> 7;
    const int row = l & 127;
    int cs = 0;
    for (int q = 0; q < qt; ++q) cs += (2*q + 2 + CHUNK - 1) / CHUNK;
    const int nch = (2*qt + 2 + CHUNK - 1) / CHUNK;

    float4 o = {0.f, 0.f, 0.f, 0.f};
    float rssum = 0.f;
    for (int ci = 0; ci < nch; ++ci) {
        const size_t slab = (size_t)(cs + ci) * 16 + nh;
        const float4 p = *(const float4*)(O_part + slab*8192 + row*64 + d4*4);
        o.x += p.x; o.y += p.y; o.z += p.z; o.w += p.w;
        rssum += rs_part[slab*128 + row];
    }
    const float inv = 1.0f / rssum;
    float4 r;
    r.x = o.x * inv; r.y = o.y * inv; r.z = o.z * inv; r.w = o.w * inv;
    const int n = nh >> 3, h = nh & 7;
    *(float4*)(out + ((size_t)(n*L_SEQ + l))*DMODEL + h*DHEAD + d4*4) = r;
}

extern "C" void kernel_launch(void* const* d_in, const int* in_sizes, int n_in,
                              void* d_out, int out_size, void* d_ws, size_t ws_size,
                              hipStream_t stream) {
    const float* y         = (const float*)d_in[0];
    const float* positions = (const float*)d_in[1];
    const float* Wq        = (const float*)d_in[2];
    const float* Wk        = (const float*)d_in[3];
    const float* Wv        = (const float*)d_in[4];
    const float* coeff     = (const float*)d_in[5];
    const float* pw        = (const float*)d_in[6];
    const float* pb        = (const float*)d_in[7];
    float* out = (float*)d_out;

    const size_t SQK = (size_t)16 * QK_STRIDE;   // shorts (8 MB)
    const size_t SV  = (size_t)16 * V_STRIDE;    // shorts (4 MB)
    const size_t SY  = (size_t)4096 * 512;       // 2M shorts (4 MB)
    const size_t SW  = (size_t)3 * 512 * 512;    // 768K shorts (1.5 MB)
    short* Qh = (short*)d_ws;
    short* Ql = Qh + SQK;
    short* Kh = Ql + SQK;
    short* Kl = Kh + SQK;
    short* Vh = Kl + SQK;
    short* Vl = Vh + SV;
    short* yh = Vl + SV;
    short* yl = yh + SY;
    short* wh = yl + SY;
    short* wl = wh + SW;
    float* O_part = (float*)(wl + SW);
    const size_t base_bytes = (SQK*4 + SV*2 + SY*2 + SW*2) * sizeof(short);
    const size_t per_slot   = (size_t)16 * (8192 + 128) * sizeof(float);

    split_kernel<<<dim3(1408), dim3(256), 0, stream>>>(y, Wq, Wk, Wv, yh, yl, wh, wl);
    prep_kernel<<<dim3(32, 8, 3), dim3(256), 0, stream>>>(
        yh, yl, wh, wl, positions, coeff, pw, pb, Qh, Ql, Kh, Kl, Vh, Vl);

    if (ws_size >= base_bytes + 72 * per_slot) {
        float* rs_part = O_part + (size_t)72 * 16 * 8192;
        attn_kernel<4><<<dim3(72 * 16), dim3(512), 0, stream>>>(
            Qh, Ql, Kh, Kl, Vh, Vl, O_part, rs_part);
        reduce_div_kernel<4><<<dim3(2048), dim3(256), 0, stream>>>(O_part, rs_part, out);
    } else {
        float* rs_part = O_part + (size_t)40 * 16 * 8192;
        attn_kernel<8><<<dim3(40 * 16), dim3(512), 0, stream>>>(
            Qh, Ql, Kh, Kl, Vh, Vl, O_part, rs_part);
        reduce_div_kernel<8><<<dim3(2048), dim3(256), 0, stream>>>(O_part, rs_part, out);
    }
}